// Round 4
// baseline (64.103 us; speedup 1.0000x reference)
//
#include <hip/hip_runtime.h>
#include <math.h>

constexpr int BATCH = 4;
constexpr int NPTS  = 8192;
constexpr int BLOCK = 256;
constexpr int P     = 4;                              // own points per thread
constexpr int OWN_TILE   = BLOCK * P;                 // 1024
constexpr int OTHER_TILE = 256;                       // cols per block
constexpr int NGRP   = OTHER_TILE / 8;                // 32 groups of 8
constexpr int GROUPS = NPTS / OWN_TILE;               // 8
constexpr int CHUNKS = NPTS / OTHER_TILE;             // 32
constexpr int BLOCKS_PER_DIR = BATCH * GROUPS * CHUNKS; // 1024
constexpr int CLOUD = BATCH * NPTS;                   // 32768

// ---------------- prep: init dmin=+inf, pack (-2x,-2y,-2z,r^2) both clouds
__global__ __launch_bounds__(256) void cd_prep(
    const float* __restrict__ xyz1, const float* __restrict__ xyz2,
    float4* __restrict__ packed, unsigned int* __restrict__ dmin) {
    const int i = blockIdx.x * blockDim.x + threadIdx.x;   // 0 .. 2*CLOUD-1
    dmin[i] = 0x7F800000u;
    const float* src = (i < CLOUD) ? xyz1 : xyz2;          // block-uniform
    const int idx = i & (CLOUD - 1);
    const float x = src[idx * 3 + 0];
    const float y = src[idx * 3 + 1];
    const float z = src[idx * 3 + 2];
    packed[i] = make_float4(-2.f * x, -2.f * y, -2.f * z, x*x + y*y + z*z);
}

// ---------------- main: no LDS; other points read at block-uniform addresses
__global__ __launch_bounds__(BLOCK, 4) void cd_min(
    const float* __restrict__ xyz1, const float* __restrict__ xyz2,
    const float4* __restrict__ packed, unsigned int* __restrict__ dmin) {

    const int bid = blockIdx.x;
    const int dir = bid >> 10;        // BLOCKS_PER_DIR == 1024
    const int lb  = bid & 1023;
    const int b   = lb >> 8;          // batch (4): GROUPS*CHUNKS = 256
    const int rem = lb & 255;
    const int grp = rem >> 5;         // own group (8)
    const int chk = rem & 31;         // other chunk (32)

    const float* own = dir ? xyz2 : xyz1;
    const float4* oth = packed + (dir ? 0 : CLOUD) + b * NPTS + chk * OTHER_TILE;
    unsigned int* dptr = dmin + dir * CLOUD;
    const int ownBase = b * NPTS + grp * OWN_TILE;

    const int t = threadIdx.x;

    // ---- own points: 4 per thread, raw coords + |p|^2
    float px0,py0,pz0, px1,py1,pz1, px2,py2,pz2, px3,py3,pz3;
    float rr0, rr1, rr2, rr3;
    {
        const float4* src =
            reinterpret_cast<const float4*>(own + (size_t)ownBase * 3) + t * 3;
        float4 a = src[0], q = src[1], c = src[2];
        px0=a.x; py0=a.y; pz0=a.z;
        px1=a.w; py1=q.x; pz1=q.y;
        px2=q.z; py2=q.w; pz2=c.x;
        px3=c.y; py3=c.z; pz3=c.w;
        rr0 = px0*px0 + py0*py0 + pz0*pz0;
        rr1 = px1*px1 + py1*py1 + pz1*pz1;
        rr2 = px2*px2 + py2*py2 + pz2*pz2;
        rr3 = px3*px3 + py3*py3 + pz3*pz3;
    }
    float ma0=INFINITY, ma1=INFINITY, ma2=INFINITY, ma3=INFINITY;
    float mb0=INFINITY, mb1=INFINITY, mb2=INFINITY, mb3=INFINITY;

    float4 qa[8], qb[8];
    auto loadg = [&](float4 (&q)[8], int g) {
        const float4* s = oth + (g << 3);
#pragma unroll
        for (int i = 0; i < 8; ++i) q[i] = s[i];
    };

    // dist^2 minus r1: q holds (-2x2,-2y2,-2z2,r2) -> r2 - 2 x1.x2
#define CD_DIST(Q, PX, PY, PZ) \
    fmaf(PX, Q.x, fmaf(PY, Q.y, fmaf(PZ, Q.z, Q.w)))

    auto comp = [&](const float4 (&q)[8]) {
#pragma unroll
        for (int cp = 0; cp < 4; ++cp) {     // column pairs (compile-time)
            const float4 u = q[2*cp], v = q[2*cp + 1];
            float a0 = CD_DIST(u, px0, py0, pz0), b0 = CD_DIST(v, px0, py0, pz0);
            float a1 = CD_DIST(u, px1, py1, pz1), b1 = CD_DIST(v, px1, py1, pz1);
            float a2 = CD_DIST(u, px2, py2, pz2), b2 = CD_DIST(v, px2, py2, pz2);
            float a3 = CD_DIST(u, px3, py3, pz3), b3 = CD_DIST(v, px3, py3, pz3);
            if (cp & 1) {
                mb0 = fminf(fminf(a0, b0), mb0);
                mb1 = fminf(fminf(a1, b1), mb1);
                mb2 = fminf(fminf(a2, b2), mb2);
                mb3 = fminf(fminf(a3, b3), mb3);
            } else {
                ma0 = fminf(fminf(a0, b0), ma0);
                ma1 = fminf(fminf(a1, b1), ma1);
                ma2 = fminf(fminf(a2, b2), ma2);
                ma3 = fminf(fminf(a3, b3), ma3);
            }
        }
    };
#undef CD_DIST

    // ---- two-buffer pipeline over 32 groups of 8 other-points
    loadg(qa, 0);
    for (int g = 0; g < NGRP - 2; g += 2) {
        loadg(qb, g + 1);
        comp(qa);
        loadg(qa, g + 2);
        comp(qb);
    }
    loadg(qb, NGRP - 1);
    comp(qa);
    comp(qb);

    // ---- publish: d = max(r1 + min, 0); uint atomicMin exact for d >= 0
    const float mv0 = fminf(ma0, mb0), mv1 = fminf(ma1, mb1);
    const float mv2 = fminf(ma2, mb2), mv3 = fminf(ma3, mb3);
    const int o = ownBase + t * P;
    atomicMin(&dptr[o + 0], __float_as_uint(fmaxf(rr0 + mv0, 0.0f)));
    atomicMin(&dptr[o + 1], __float_as_uint(fmaxf(rr1 + mv1, 0.0f)));
    atomicMin(&dptr[o + 2], __float_as_uint(fmaxf(rr2 + mv2, 0.0f)));
    atomicMin(&dptr[o + 3], __float_as_uint(fmaxf(rr3 + mv3, 0.0f)));
}

// ---------------- final: deterministic sum + means
__global__ __launch_bounds__(1024) void cd_reduce(
    const float* __restrict__ dm /* 2*CLOUD floats */, float* __restrict__ out) {
    __shared__ float sw[16];
    const int t = threadIdx.x;
    const float4* v = reinterpret_cast<const float4*>(dm);
    float s = 0.0f;
#pragma unroll 4
    for (int i = t; i < 2 * CLOUD / 4; i += 1024) {
        float4 x = v[i];
        s += (x.x + x.y) + (x.z + x.w);
    }
#pragma unroll
    for (int off = 32; off > 0; off >>= 1) s += __shfl_down(s, off, 64);
    if ((t & 63) == 0) sw[t >> 6] = s;
    __syncthreads();
    if (t == 0) {
        float tot = 0.0f;
#pragma unroll
        for (int w = 0; w < 16; ++w) tot += sw[w];
        out[0] = tot / (float)CLOUD;
    }
}

extern "C" void kernel_launch(void* const* d_in, const int* in_sizes, int n_in,
                              void* d_out, int out_size, void* d_ws, size_t ws_size,
                              hipStream_t stream) {
    const float* xyz1 = (const float*)d_in[0];
    const float* xyz2 = (const float*)d_in[1];
    unsigned int* dmin = (unsigned int*)d_ws;                    // 256 KB
    float4* packed = (float4*)((char*)d_ws + 2 * CLOUD * 4);     // 1 MB
    float* out = (float*)d_out;

    cd_prep<<<2 * CLOUD / 256, 256, 0, stream>>>(xyz1, xyz2, packed, dmin);
    cd_min<<<2 * BLOCKS_PER_DIR, BLOCK, 0, stream>>>(xyz1, xyz2, packed, dmin);
    cd_reduce<<<1, 1024, 0, stream>>>((const float*)dmin, out);
}

// Round 5
// 44.483 us; speedup vs baseline: 1.4411x; 1.4411x over previous
//
#include <hip/hip_runtime.h>
#include <math.h>

typedef short  bf16x8 __attribute__((ext_vector_type(8)));
typedef float  f32x16 __attribute__((ext_vector_type(16)));

constexpr int BATCH = 4, NPTS = 8192;
constexpr int CLOUD = BATCH * NPTS;     // 32768 points per cloud

__device__ inline unsigned short bf16_rne(float x) {
    unsigned int u = __float_as_uint(x);
    return (unsigned short)((u + 0x7FFFu + ((u >> 16) & 1u)) >> 16);
}
__device__ inline float bf16_val(unsigned short h) {
    return __uint_as_float(((unsigned int)h) << 16);
}

// ---------------- prep: init dist=+inf; build A-role / B-role bf16 packs.
// K=16 slots. A[n]: [hx,lx,hx, hy,ly,hy, hz,lz,hz, 1,1,1, r0,r1,r2, 0]
//             B[m]: [htx,htx,ltx, hty,hty,lty, htz,htz,ltz, s0,s1,s2, 1,1,1, 0]
// (t = -2*coord; r,s = 3-way bf16 splits of |p|^2)  =>  sum_k A*B ~= d^2.
__global__ __launch_bounds__(256) void cd_prep(
    const float* __restrict__ x1, const float* __restrict__ x2,
    uint4* __restrict__ APK, uint4* __restrict__ BPK,
    unsigned int* __restrict__ dist) {
    const int i = blockIdx.x * 256 + threadIdx.x;   // 0 .. 2*CLOUD-1
    dist[i] = 0x7F800000u;                          // +inf
    const float* src = (i < CLOUD) ? x1 : x2;
    const int idx = i & (CLOUD - 1);
    const float x = src[idx*3+0], y = src[idx*3+1], z = src[idx*3+2];
    const float r = x*x + y*y + z*z;

    const unsigned short one = 0x3F80u;
    // r 3-way split
    const unsigned short r0 = bf16_rne(r);
    const float rm1 = r - bf16_val(r0);
    const unsigned short r1 = bf16_rne(rm1);
    const unsigned short r2 = bf16_rne(rm1 - bf16_val(r1));

    // A-role: +coords hi/lo
    const unsigned short hx = bf16_rne(x), hy = bf16_rne(y), hz = bf16_rne(z);
    const unsigned short lx = bf16_rne(x - bf16_val(hx));
    const unsigned short ly = bf16_rne(y - bf16_val(hy));
    const unsigned short lz = bf16_rne(z - bf16_val(hz));
    uint4 a0, a1;
    a0.x = (unsigned)hx | ((unsigned)lx << 16);
    a0.y = (unsigned)hx | ((unsigned)hy << 16);
    a0.z = (unsigned)ly | ((unsigned)hy << 16);
    a0.w = (unsigned)hz | ((unsigned)lz << 16);
    a1.x = (unsigned)hz | ((unsigned)one << 16);
    a1.y = (unsigned)one | ((unsigned)one << 16);
    a1.z = (unsigned)r0 | ((unsigned)r1 << 16);
    a1.w = (unsigned)r2;
    APK[2*i+0] = a0;  APK[2*i+1] = a1;

    // B-role: t = -2*coords hi/lo
    const float tx = -2.f*x, ty = -2.f*y, tz = -2.f*z;
    const unsigned short ax = bf16_rne(tx), ay = bf16_rne(ty), az = bf16_rne(tz);
    const unsigned short bx = bf16_rne(tx - bf16_val(ax));
    const unsigned short by = bf16_rne(ty - bf16_val(ay));
    const unsigned short bz = bf16_rne(tz - bf16_val(az));
    uint4 b0, b1;
    b0.x = (unsigned)ax | ((unsigned)ax << 16);
    b0.y = (unsigned)bx | ((unsigned)ay << 16);
    b0.z = (unsigned)ay | ((unsigned)by << 16);
    b0.w = (unsigned)az | ((unsigned)az << 16);
    b1.x = (unsigned)bz | ((unsigned)r0 << 16);
    b1.y = (unsigned)r1 | ((unsigned)r2 << 16);
    b1.z = (unsigned)one | ((unsigned)one << 16);
    b1.w = (unsigned)one;
    BPK[2*i+0] = b0;  BPK[2*i+1] = b1;
}

// ---------------- gemm+min: wave = 128 rows x 1024-col sweep, MFMA 32x32x16.
// wid bits: dir(1) | b(2) | cc(3) | rg(6). Block's 4 waves share B stream.
__global__ __launch_bounds__(256) void cd_gemm(
    const uint4* __restrict__ APK, const uint4* __restrict__ BPK,
    unsigned int* __restrict__ dist) {

    __shared__ float lbuf[4][32][33];

    const int tid = threadIdx.x;
    const int wv  = tid >> 6;
    const int l   = tid & 63;
    const int lane31 = l & 31, half = l >> 5;

    const int wid = blockIdx.x * 4 + wv;       // 0..4095
    const int dir = wid >> 11;
    const int b   = (wid >> 9) & 3;
    const int cc  = (wid >> 6) & 7;
    const int rg  = wid & 63;

    const int aBase = (dir ? CLOUD : 0) + b * NPTS + rg * 128;
    const int bBase = (dir ? 0 : CLOUD) + b * NPTS + cc * 1024;

    // A fragments: lane supplies row = l&31, k-slice = 8*half..+7
    bf16x8 afr[4];
#pragma unroll
    for (int f = 0; f < 4; ++f) {
        uint4 v = APK[(size_t)(aBase + f*32 + lane31) * 2 + half];
        __builtin_memcpy(&afr[f], &v, 16);
    }

    f32x16 zc;
#pragma unroll
    for (int i = 0; i < 16; ++i) zc[i] = 0.0f;

    float racc[4][16];
#pragma unroll
    for (int f = 0; f < 4; ++f)
#pragma unroll
        for (int r = 0; r < 16; ++r) racc[f][r] = INFINITY;

    // tile-pair sweep: pair p covers cols bBase + p*64 .. +63
    uint4 nA = BPK[(size_t)(bBase +  0 + lane31) * 2 + half];
    uint4 nB = BPK[(size_t)(bBase + 32 + lane31) * 2 + half];
    for (int p = 0; p < 16; ++p) {
        bf16x8 bA, bB;
        __builtin_memcpy(&bA, &nA, 16);
        __builtin_memcpy(&bB, &nB, 16);
        const int np = (p + 1) & 15;           // last iter reloads pair 0 (harmless)
        nA = BPK[(size_t)(bBase + np*64 +  0 + lane31) * 2 + half];
        nB = BPK[(size_t)(bBase + np*64 + 32 + lane31) * 2 + half];
#pragma unroll
        for (int f = 0; f < 4; ++f) {
            f32x16 cA = __builtin_amdgcn_mfma_f32_32x32x16_bf16(afr[f], bA, zc, 0, 0, 0);
            f32x16 cB = __builtin_amdgcn_mfma_f32_32x32x16_bf16(afr[f], bB, zc, 0, 0, 0);
#pragma unroll
            for (int r = 0; r < 16; ++r)
                racc[f][r] = fminf(fminf(cA[r], cB[r]), racc[f][r]);  // v_min3
        }
    }

    // epilogue: per frag, LDS transpose (33-stride, conflict-free) + row reduce
    const int distBase = dir * CLOUD + b * NPTS + rg * 128;
#pragma unroll
    for (int f = 0; f < 4; ++f) {
#pragma unroll
        for (int r = 0; r < 16; ++r) {
            const int rl = (r & 3) + 8 * (r >> 2) + 4 * half;  // C/D row map
            lbuf[wv][rl][lane31] = racc[f][r];
        }
        // same-wave DS ops are in-order; compiler inserts lgkmcnt waits
        const int row = l >> 1;
        float m = INFINITY;
#pragma unroll
        for (int i = 0; i < 16; ++i)
            m = fminf(m, lbuf[wv][row][(l & 1) * 16 + i]);
        m = fminf(m, __shfl_xor(m, 1, 64));
        if ((l & 1) == 0)
            atomicMin(&dist[distBase + f * 32 + row],
                      __float_as_uint(fmaxf(m, 0.0f)));
    }
}

// ---------------- final: deterministic sum + means
__global__ __launch_bounds__(1024) void cd_reduce(
    const float* __restrict__ dm /* 2*CLOUD floats */, float* __restrict__ out) {
    __shared__ float sw[16];
    const int t = threadIdx.x;
    const float4* v = reinterpret_cast<const float4*>(dm);
    float s = 0.0f;
#pragma unroll 4
    for (int i = t; i < 2 * CLOUD / 4; i += 1024) {
        float4 x = v[i];
        s += (x.x + x.y) + (x.z + x.w);
    }
#pragma unroll
    for (int off = 32; off > 0; off >>= 1) s += __shfl_down(s, off, 64);
    if ((t & 63) == 0) sw[t >> 6] = s;
    __syncthreads();
    if (t == 0) {
        float tot = 0.0f;
#pragma unroll
        for (int w = 0; w < 16; ++w) tot += sw[w];
        out[0] = tot / (float)CLOUD;
    }
}

extern "C" void kernel_launch(void* const* d_in, const int* in_sizes, int n_in,
                              void* d_out, int out_size, void* d_ws, size_t ws_size,
                              hipStream_t stream) {
    const float* xyz1 = (const float*)d_in[0];
    const float* xyz2 = (const float*)d_in[1];
    unsigned int* dist = (unsigned int*)d_ws;                       // 256 KB
    uint4* APK = (uint4*)((char*)d_ws + 2u * CLOUD * 4u);           // 2 MB
    uint4* BPK = (uint4*)((char*)d_ws + 2u * CLOUD * 4u + 2u * CLOUD * 32u); // 2 MB
    float* out = (float*)d_out;

    cd_prep<<<2 * CLOUD / 256, 256, 0, stream>>>(xyz1, xyz2, APK, BPK, dist);
    cd_gemm<<<1024, 256, 0, stream>>>(APK, BPK, dist);
    cd_reduce<<<1, 1024, 0, stream>>>((const float*)dist, out);
}